// Round 6
// baseline (267.801 us; speedup 1.0000x reference)
//
#include <hip/hip_runtime.h>
#include <math.h>

#define ROWS 8192
#define NCOL 2048
#define V 32
#define WPB 4                 // waves (rows) per block
#define THREADS (WPB * 64)

// DPP ctrl encodings (gfx9/CDNA): quad_perm value = p0|p1<<2|p2<<4|p3<<6
#define DPP_XOR1 0xB1         // quad_perm [1,0,3,2]
#define DPP_XOR2 0x4E         // quad_perm [2,3,0,1]
#define DPP_XOR3 0x1B         // quad_perm [3,2,1,0]
#define DPP_XOR7 0x141        // row_half_mirror (xor 7 within 8)
#define DPP_XOR15 0x140       // row_mirror (xor 15 within 16)

// static compare-exchange: ascending, both indices compile-time
__device__ __forceinline__ void ce(float& a, float& b) {
  const float lo = fminf(a, b);
  const float hi = fmaxf(a, b);
  a = lo; b = hi;
}

// med3(a,b,-inf)=min; med3(a,b,+inf)=max. One VALU op per directed CE.
__device__ __forceinline__ float ce_dir(float a, float b, float cdir) {
  return __builtin_amdgcn_fmed3f(a, b, cdir);
}

__device__ __forceinline__ float dirc(int lane, int bit) {
  return (lane & bit) ? INFINITY : -INFINITY;
}

// lane-xor exchange on the VALU pipe (v_mov_b32_dpp), NOT the DS pipe
template <int CTRL>
__device__ __forceinline__ float dpp_x(float x) {
  return __int_as_float(__builtin_amdgcn_update_dpp(
      0, __float_as_int(x), CTRL, 0xF, 0xF, true));
}

// lane exchange on DS pipe; addr = (lane^mask)<<2, hoisted per pass
__device__ __forceinline__ float bperm(int addr, float x) {
  return __int_as_float(__builtin_amdgcn_ds_bpermute(addr, __float_as_int(x)));
}

// xor pass (same reg index v), DPP variant
template <int CTRL>
__device__ __forceinline__ void dpp_xor_pass(float r[V], float cdir) {
#pragma unroll
  for (int v = 0; v < V; ++v) r[v] = ce_dir(r[v], dpp_x<CTRL>(r[v]), cdir);
}

// flip pass (reg partner v^31), DPP variant; hazard-free 8-reg units
template <int CTRL>
__device__ __forceinline__ void dpp_flip_pass(float r[V], float cdir) {
#pragma unroll
  for (int q = 0; q < 4; ++q) {
    float o[8];
#pragma unroll
    for (int u = 0; u < 4; ++u) {
      o[u]     = dpp_x<CTRL>(r[(4 * q + u) ^ 31]);
      o[u + 4] = dpp_x<CTRL>(r[4 * q + u]);
    }
#pragma unroll
    for (int u = 0; u < 4; ++u) {
      r[4 * q + u]        = ce_dir(r[4 * q + u],        o[u],     cdir);
      r[(4 * q + u) ^ 31] = ce_dir(r[(4 * q + u) ^ 31], o[u + 4], cdir);
    }
  }
}

// xor pass, DS variant
__device__ __forceinline__ void ds_xor_pass(float r[V], int addr, float cdir) {
#pragma unroll
  for (int c = 0; c < V; c += 8) {
    float o[8];
#pragma unroll
    for (int u = 0; u < 8; ++u) o[u] = bperm(addr, r[c + u]);
#pragma unroll
    for (int u = 0; u < 8; ++u) r[c + u] = ce_dir(r[c + u], o[u], cdir);
  }
}

// flip pass, DS variant
__device__ __forceinline__ void ds_flip_pass(float r[V], int addr, float cdir) {
#pragma unroll
  for (int q = 0; q < 4; ++q) {
    float o[8];
#pragma unroll
    for (int u = 0; u < 4; ++u) {
      o[u]     = bperm(addr, r[(4 * q + u) ^ 31]);
      o[u + 4] = bperm(addr, r[4 * q + u]);
    }
#pragma unroll
    for (int u = 0; u < 4; ++u) {
      r[4 * q + u]        = ce_dir(r[4 * q + u],        o[u],     cdir);
      r[(4 * q + u) ^ 31] = ce_dir(r[(4 * q + u) ^ 31], o[u + 4], cdir);
    }
  }
}

// in-lane xor passes j=16..1: static indices and directions
__device__ __forceinline__ void inlane_tail(float rp[V], float rt[V]) {
#pragma unroll
  for (int j = 16; j >= 1; j >>= 1) {
#pragma unroll
    for (int v = 0; v < V; ++v) {
      if ((v & j) == 0) {
        ce(rp[v], rp[v | j]);
        ce(rt[v], rt[v | j]);
      }
    }
  }
}

__global__ __launch_bounds__(THREADS, 4) void sort_mse_kernel(
    const float* __restrict__ pred, const float* __restrict__ targ,
    float* __restrict__ out) {
  const int lane = threadIdx.x & 63;
  const int wave = threadIdx.x >> 6;
  const int row = blockIdx.x * WPB + wave;
  const size_t base = (size_t)row * NCOL + (size_t)lane * V;

  float rp[V], rt[V];
  const float4* p4 = (const float4*)(pred + base);
  const float4* t4 = (const float4*)(targ + base);
#pragma unroll
  for (int q = 0; q < V / 4; ++q) {
    const float4 a = p4[q];
    rp[4 * q + 0] = a.x; rp[4 * q + 1] = a.y;
    rp[4 * q + 2] = a.z; rp[4 * q + 3] = a.w;
    const float4 b = t4[q];
    rt[4 * q + 0] = b.x; rt[4 * q + 1] = b.y;
    rt[4 * q + 2] = b.z; rt[4 * q + 3] = b.w;
  }

  // ---- Phase 1: stages k = 2..32, fully in-lane, fully static ----
#pragma unroll
  for (int k = 2; k <= V; k <<= 1) {
#pragma unroll
    for (int v = 0; v < V; ++v) {
      if ((v & (k >> 1)) == 0) {
        ce(rp[v], rp[v ^ (k - 1)]);
        ce(rt[v], rt[v ^ (k - 1)]);
      }
    }
#pragma unroll
    for (int j = k >> 2; j >= 1; j >>= 1) {
#pragma unroll
      for (int v = 0; v < V; ++v) {
        if ((v & j) == 0) {
          ce(rp[v], rp[v | j]);
          ce(rt[v], rt[v | j]);
        }
      }
    }
  }

  // ---- Phase 2: merge stages kb = k/64 = 1..32 ----
  // flip lane-mask = 2kb-1, dir bit kb; xor passes m = kb/2..1, dir bit m.
  // lm,m in {1,2,3,7,15} -> DPP (VALU pipe); {4,8,16,31,63} -> ds_bpermute.

  { // kb = 1
    const float c1 = dirc(lane, 1);
    dpp_flip_pass<DPP_XOR1>(rp, c1); dpp_flip_pass<DPP_XOR1>(rt, c1);
    inlane_tail(rp, rt);
  }
  { // kb = 2
    const float c2 = dirc(lane, 2);
    dpp_flip_pass<DPP_XOR3>(rp, c2); dpp_flip_pass<DPP_XOR3>(rt, c2);
    const float c1 = dirc(lane, 1);
    dpp_xor_pass<DPP_XOR1>(rp, c1); dpp_xor_pass<DPP_XOR1>(rt, c1);
    inlane_tail(rp, rt);
  }
  { // kb = 4
    const float c4 = dirc(lane, 4);
    dpp_flip_pass<DPP_XOR7>(rp, c4); dpp_flip_pass<DPP_XOR7>(rt, c4);
    const float c2 = dirc(lane, 2);
    dpp_xor_pass<DPP_XOR2>(rp, c2); dpp_xor_pass<DPP_XOR2>(rt, c2);
    const float c1 = dirc(lane, 1);
    dpp_xor_pass<DPP_XOR1>(rp, c1); dpp_xor_pass<DPP_XOR1>(rt, c1);
    inlane_tail(rp, rt);
  }
  { // kb = 8
    const float c8 = dirc(lane, 8);
    dpp_flip_pass<DPP_XOR15>(rp, c8); dpp_flip_pass<DPP_XOR15>(rt, c8);
    const int a4 = ((lane ^ 4) << 2);
    const float c4 = dirc(lane, 4);
    ds_xor_pass(rp, a4, c4); ds_xor_pass(rt, a4, c4);
    const float c2 = dirc(lane, 2);
    dpp_xor_pass<DPP_XOR2>(rp, c2); dpp_xor_pass<DPP_XOR2>(rt, c2);
    const float c1 = dirc(lane, 1);
    dpp_xor_pass<DPP_XOR1>(rp, c1); dpp_xor_pass<DPP_XOR1>(rt, c1);
    inlane_tail(rp, rt);
  }
  { // kb = 16
    const int a31 = ((lane ^ 31) << 2);
    const float c16 = dirc(lane, 16);
    ds_flip_pass(rp, a31, c16); ds_flip_pass(rt, a31, c16);
    const int a8 = ((lane ^ 8) << 2);
    const float c8 = dirc(lane, 8);
    ds_xor_pass(rp, a8, c8); ds_xor_pass(rt, a8, c8);
    const int a4 = ((lane ^ 4) << 2);
    const float c4 = dirc(lane, 4);
    ds_xor_pass(rp, a4, c4); ds_xor_pass(rt, a4, c4);
    const float c2 = dirc(lane, 2);
    dpp_xor_pass<DPP_XOR2>(rp, c2); dpp_xor_pass<DPP_XOR2>(rt, c2);
    const float c1 = dirc(lane, 1);
    dpp_xor_pass<DPP_XOR1>(rp, c1); dpp_xor_pass<DPP_XOR1>(rt, c1);
    inlane_tail(rp, rt);
  }
  { // kb = 32
    const int a63 = ((lane ^ 63) << 2);
    const float c32 = dirc(lane, 32);
    ds_flip_pass(rp, a63, c32); ds_flip_pass(rt, a63, c32);
    const int a16 = ((lane ^ 16) << 2);
    const float c16 = dirc(lane, 16);
    ds_xor_pass(rp, a16, c16); ds_xor_pass(rt, a16, c16);
    const int a8 = ((lane ^ 8) << 2);
    const float c8 = dirc(lane, 8);
    ds_xor_pass(rp, a8, c8); ds_xor_pass(rt, a8, c8);
    const int a4 = ((lane ^ 4) << 2);
    const float c4 = dirc(lane, 4);
    ds_xor_pass(rp, a4, c4); ds_xor_pass(rt, a4, c4);
    const float c2 = dirc(lane, 2);
    dpp_xor_pass<DPP_XOR2>(rp, c2); dpp_xor_pass<DPP_XOR2>(rt, c2);
    const float c1 = dirc(lane, 1);
    dpp_xor_pass<DPP_XOR1>(rp, c1); dpp_xor_pass<DPP_XOR1>(rt, c1);
    inlane_tail(rp, rt);
  }

  // ranks are matched at identical (lane, v) after both sorts
  float acc = 0.f;
#pragma unroll
  for (int v = 0; v < V; ++v) {
    const float d = rp[v] - rt[v];
    acc = fmaf(d, d, acc);
  }
#pragma unroll
  for (int off = 32; off > 0; off >>= 1) acc += __shfl_down(acc, off, 64);
  if (lane == 0) {
    unsafeAtomicAdd(out, acc * (1.0f / ((float)ROWS * (float)NCOL)));
  }
}

extern "C" void kernel_launch(void* const* d_in, const int* in_sizes, int n_in,
                              void* d_out, int out_size, void* d_ws, size_t ws_size,
                              hipStream_t stream) {
  const float* pred = (const float*)d_in[0];
  const float* targ = (const float*)d_in[1];
  float* out = (float*)d_out;

  hipMemsetAsync(out, 0, sizeof(float), stream);  // d_out is re-poisoned 0xAA
  sort_mse_kernel<<<ROWS / WPB, THREADS, 0, stream>>>(pred, targ, out);
}

// Round 7
// 253.304 us; speedup vs baseline: 1.0572x; 1.0572x over previous
//
#include <hip/hip_runtime.h>
#include <math.h>

#define ROWS 8192
#define NCOL 2048
#define V 32
#define WPB 4                 // waves (rows) per block
#define THREADS (WPB * 64)

// DPP ctrl encodings (gfx9/CDNA): quad_perm value = p0|p1<<2|p2<<4|p3<<6
#define DPP_XOR1 0xB1         // quad_perm [1,0,3,2]
#define DPP_XOR2 0x4E         // quad_perm [2,3,0,1]
#define DPP_XOR3 0x1B         // quad_perm [3,2,1,0]
#define DPP_XOR7 0x141        // row_half_mirror (xor 7 within 8)
#define DPP_XOR15 0x140       // row_mirror (xor 15 within 16)

// static compare-exchange: ascending, both indices compile-time
__device__ __forceinline__ void ce(float& a, float& b) {
  const float lo = fminf(a, b);
  const float hi = fmaxf(a, b);
  a = lo; b = hi;
}

// med3(a,b,-inf)=min; med3(a,b,+inf)=max. One VALU op per directed CE.
__device__ __forceinline__ float ce_dir(float a, float b, float cdir) {
  return __builtin_amdgcn_fmed3f(a, b, cdir);
}

__device__ __forceinline__ float dirc(int lane, int bit) {
  return (lane & bit) ? INFINITY : -INFINITY;
}

// lane-xor exchange on the VALU pipe (v_mov_b32_dpp), NOT the DS pipe
template <int CTRL>
__device__ __forceinline__ float dpp_x(float x) {
  return __int_as_float(__builtin_amdgcn_update_dpp(
      0, __float_as_int(x), CTRL, 0xF, 0xF, true));
}

// lane exchange on DS pipe; addr = (lane^mask)<<2, hoisted per pass
__device__ __forceinline__ float bperm(int addr, float x) {
  return __int_as_float(__builtin_amdgcn_ds_bpermute(addr, __float_as_int(x)));
}

// xor pass (same reg index v), DPP variant
template <int CTRL>
__device__ __forceinline__ void dpp_xor_pass(float r[V], float cdir) {
#pragma unroll
  for (int v = 0; v < V; ++v) r[v] = ce_dir(r[v], dpp_x<CTRL>(r[v]), cdir);
}

// flip pass (reg partner v^31), DPP variant; hazard-free 8-reg units
template <int CTRL>
__device__ __forceinline__ void dpp_flip_pass(float r[V], float cdir) {
#pragma unroll
  for (int q = 0; q < 4; ++q) {
    float o[8];
#pragma unroll
    for (int u = 0; u < 4; ++u) {
      o[u]     = dpp_x<CTRL>(r[(4 * q + u) ^ 31]);
      o[u + 4] = dpp_x<CTRL>(r[4 * q + u]);
    }
#pragma unroll
    for (int u = 0; u < 4; ++u) {
      r[4 * q + u]        = ce_dir(r[4 * q + u],        o[u],     cdir);
      r[(4 * q + u) ^ 31] = ce_dir(r[(4 * q + u) ^ 31], o[u + 4], cdir);
    }
  }
}

// xor pass, DS variant
__device__ __forceinline__ void ds_xor_pass(float r[V], int addr, float cdir) {
#pragma unroll
  for (int c = 0; c < V; c += 8) {
    float o[8];
#pragma unroll
    for (int u = 0; u < 8; ++u) o[u] = bperm(addr, r[c + u]);
#pragma unroll
    for (int u = 0; u < 8; ++u) r[c + u] = ce_dir(r[c + u], o[u], cdir);
  }
}

// flip pass, DS variant
__device__ __forceinline__ void ds_flip_pass(float r[V], int addr, float cdir) {
#pragma unroll
  for (int q = 0; q < 4; ++q) {
    float o[8];
#pragma unroll
    for (int u = 0; u < 4; ++u) {
      o[u]     = bperm(addr, r[(4 * q + u) ^ 31]);
      o[u + 4] = bperm(addr, r[4 * q + u]);
    }
#pragma unroll
    for (int u = 0; u < 4; ++u) {
      r[4 * q + u]        = ce_dir(r[4 * q + u],        o[u],     cdir);
      r[(4 * q + u) ^ 31] = ce_dir(r[(4 * q + u) ^ 31], o[u + 4], cdir);
    }
  }
}

// in-lane xor passes j=16..1: static indices and directions
__device__ __forceinline__ void inlane_tail(float rp[V], float rt[V]) {
#pragma unroll
  for (int j = 16; j >= 1; j >>= 1) {
#pragma unroll
    for (int v = 0; v < V; ++v) {
      if ((v & j) == 0) {
        ce(rp[v], rp[v | j]);
        ce(rt[v], rt[v | j]);
      }
    }
  }
}

__global__ __launch_bounds__(THREADS, 4) void sort_mse_kernel(
    const float* __restrict__ pred, const float* __restrict__ targ,
    float* __restrict__ out) {
  const int lane = threadIdx.x & 63;
  const int wave = threadIdx.x >> 6;
  const int row = blockIdx.x * WPB + wave;
  const size_t base = (size_t)row * NCOL + (size_t)lane * V;

  float rp[V], rt[V];
  const float4* p4 = (const float4*)(pred + base);
  const float4* t4 = (const float4*)(targ + base);
#pragma unroll
  for (int q = 0; q < V / 4; ++q) {
    const float4 a = p4[q];
    rp[4 * q + 0] = a.x; rp[4 * q + 1] = a.y;
    rp[4 * q + 2] = a.z; rp[4 * q + 3] = a.w;
    const float4 b = t4[q];
    rt[4 * q + 0] = b.x; rt[4 * q + 1] = b.y;
    rt[4 * q + 2] = b.z; rt[4 * q + 3] = b.w;
  }

  // ---- Phase 1: stages k = 2..32, fully in-lane, fully static ----
#pragma unroll
  for (int k = 2; k <= V; k <<= 1) {
#pragma unroll
    for (int v = 0; v < V; ++v) {
      if ((v & (k >> 1)) == 0) {
        ce(rp[v], rp[v ^ (k - 1)]);
        ce(rt[v], rt[v ^ (k - 1)]);
      }
    }
#pragma unroll
    for (int j = k >> 2; j >= 1; j >>= 1) {
#pragma unroll
      for (int v = 0; v < V; ++v) {
        if ((v & j) == 0) {
          ce(rp[v], rp[v | j]);
          ce(rt[v], rt[v | j]);
        }
      }
    }
  }

  // ---- Phase 2: merge stages kb = k/64 = 1..32 ----
  // Compact runtime loops (NO unrolling: keep the hot body inside I-cache —
  // full unroll of this phase regressed 152->171 us in round 6).
  // Pass dispatch: lane-masks {1,2,3,7,15} -> DPP (per-SIMD VALU pipe),
  // {4,8,16,31,63} -> ds_bpermute (shared per-CU DS pipe).
#pragma unroll 1
  for (int kb = 1; kb <= 32; kb <<= 1) {
    const float cf = dirc(lane, kb);
    if (kb == 1) {
      dpp_flip_pass<DPP_XOR1>(rp, cf);  dpp_flip_pass<DPP_XOR1>(rt, cf);
    } else if (kb == 2) {
      dpp_flip_pass<DPP_XOR3>(rp, cf);  dpp_flip_pass<DPP_XOR3>(rt, cf);
    } else if (kb == 4) {
      dpp_flip_pass<DPP_XOR7>(rp, cf);  dpp_flip_pass<DPP_XOR7>(rt, cf);
    } else if (kb == 8) {
      dpp_flip_pass<DPP_XOR15>(rp, cf); dpp_flip_pass<DPP_XOR15>(rt, cf);
    } else {
      const int a = ((lane ^ (2 * kb - 1)) << 2);
      ds_flip_pass(rp, a, cf); ds_flip_pass(rt, a, cf);
    }
#pragma unroll 1
    for (int m = kb >> 1; m >= 1; m >>= 1) {
      const float c = dirc(lane, m);
      if (m == 1) {
        dpp_xor_pass<DPP_XOR1>(rp, c); dpp_xor_pass<DPP_XOR1>(rt, c);
      } else if (m == 2) {
        dpp_xor_pass<DPP_XOR2>(rp, c); dpp_xor_pass<DPP_XOR2>(rt, c);
      } else {
        const int a = ((lane ^ m) << 2);
        ds_xor_pass(rp, a, c); ds_xor_pass(rt, a, c);
      }
    }
    inlane_tail(rp, rt);
  }

  // ranks are matched at identical (lane, v) after both sorts
  float acc = 0.f;
#pragma unroll
  for (int v = 0; v < V; ++v) {
    const float d = rp[v] - rt[v];
    acc = fmaf(d, d, acc);
  }
#pragma unroll
  for (int off = 32; off > 0; off >>= 1) acc += __shfl_down(acc, off, 64);
  if (lane == 0) {
    unsafeAtomicAdd(out, acc * (1.0f / ((float)ROWS * (float)NCOL)));
  }
}

extern "C" void kernel_launch(void* const* d_in, const int* in_sizes, int n_in,
                              void* d_out, int out_size, void* d_ws, size_t ws_size,
                              hipStream_t stream) {
  const float* pred = (const float*)d_in[0];
  const float* targ = (const float*)d_in[1];
  float* out = (float*)d_out;

  hipMemsetAsync(out, 0, sizeof(float), stream);  // d_out is re-poisoned 0xAA
  sort_mse_kernel<<<ROWS / WPB, THREADS, 0, stream>>>(pred, targ, out);
}

// Round 8
// 248.734 us; speedup vs baseline: 1.0767x; 1.0184x over previous
//
#include <hip/hip_runtime.h>
#include <math.h>

#define ROWS 8192
#define NCOL 2048
#define V 32
#define WPB 4                 // waves (rows) per block
#define THREADS (WPB * 64)

// DPP ctrl encodings (gfx9/CDNA): quad_perm value = p0|p1<<2|p2<<4|p3<<6
#define DPP_XOR1 0xB1         // quad_perm [1,0,3,2]
#define DPP_XOR2 0x4E         // quad_perm [2,3,0,1]
#define DPP_XOR3 0x1B         // quad_perm [3,2,1,0]
#define DPP_XOR7 0x141        // row_half_mirror (xor 7 within 8)
#define DPP_XOR15 0x140       // row_mirror (xor 15 within 16)

// static compare-exchange: ascending, both indices compile-time
__device__ __forceinline__ void ce(float& a, float& b) {
  const float lo = fminf(a, b);
  const float hi = fmaxf(a, b);
  a = lo; b = hi;
}

// med3(a,b,-inf)=min; med3(a,b,+inf)=max. One VALU op per directed CE.
__device__ __forceinline__ float ce_dir(float a, float b, float cdir) {
  return __builtin_amdgcn_fmed3f(a, b, cdir);
}

__device__ __forceinline__ float dirc(int lane, int bit) {
  return (lane & bit) ? INFINITY : -INFINITY;
}

// lane-xor exchange on the VALU pipe (v_mov_b32_dpp), NOT the DS pipe
template <int CTRL>
__device__ __forceinline__ float dpp_x(float x) {
  return __int_as_float(__builtin_amdgcn_update_dpp(
      0, __float_as_int(x), CTRL, 0xF, 0xF, true));
}

// lane exchange on DS pipe; addr = (lane^mask)<<2, hoisted per pass
__device__ __forceinline__ float bperm(int addr, float x) {
  return __int_as_float(__builtin_amdgcn_ds_bpermute(addr, __float_as_int(x)));
}

// xor pass (same reg index v), DPP variant
template <int CTRL>
__device__ __forceinline__ void dpp_xor_pass(float r[V], float cdir) {
#pragma unroll
  for (int v = 0; v < V; ++v) r[v] = ce_dir(r[v], dpp_x<CTRL>(r[v]), cdir);
}

// flip pass (reg partner v^31), DPP variant.
// 4-reg self-contained units {2q, 2q+1, 30-2q, 31-2q}: only o[4] live at once
// (round 7's o[8] units pushed the allocator into scratch spill).
template <int CTRL>
__device__ __forceinline__ void dpp_flip_pass(float r[V], float cdir) {
#pragma unroll
  for (int q = 0; q < 8; ++q) {
    const int vA = 2 * q, vB = 2 * q + 1;
    float o[4];
    o[0] = dpp_x<CTRL>(r[vA ^ 31]);
    o[1] = dpp_x<CTRL>(r[vB ^ 31]);
    o[2] = dpp_x<CTRL>(r[vB]);
    o[3] = dpp_x<CTRL>(r[vA]);
    r[vA]      = ce_dir(r[vA],      o[0], cdir);
    r[vB]      = ce_dir(r[vB],      o[1], cdir);
    r[vB ^ 31] = ce_dir(r[vB ^ 31], o[2], cdir);
    r[vA ^ 31] = ce_dir(r[vA ^ 31], o[3], cdir);
  }
}

// xor pass, DS variant (8-batch was spill-free in round 5; keep)
__device__ __forceinline__ void ds_xor_pass(float r[V], int addr, float cdir) {
#pragma unroll
  for (int c = 0; c < V; c += 8) {
    float o[8];
#pragma unroll
    for (int u = 0; u < 8; ++u) o[u] = bperm(addr, r[c + u]);
#pragma unroll
    for (int u = 0; u < 8; ++u) r[c + u] = ce_dir(r[c + u], o[u], cdir);
  }
}

// flip pass, DS variant; 4-reg units (see dpp_flip_pass note)
__device__ __forceinline__ void ds_flip_pass(float r[V], int addr, float cdir) {
#pragma unroll
  for (int q = 0; q < 8; ++q) {
    const int vA = 2 * q, vB = 2 * q + 1;
    float o[4];
    o[0] = bperm(addr, r[vA ^ 31]);
    o[1] = bperm(addr, r[vB ^ 31]);
    o[2] = bperm(addr, r[vB]);
    o[3] = bperm(addr, r[vA]);
    r[vA]      = ce_dir(r[vA],      o[0], cdir);
    r[vB]      = ce_dir(r[vB],      o[1], cdir);
    r[vB ^ 31] = ce_dir(r[vB ^ 31], o[2], cdir);
    r[vA ^ 31] = ce_dir(r[vA ^ 31], o[3], cdir);
  }
}

// in-lane xor passes j=16..1: static indices and directions
__device__ __forceinline__ void inlane_tail(float rp[V], float rt[V]) {
#pragma unroll
  for (int j = 16; j >= 1; j >>= 1) {
#pragma unroll
    for (int v = 0; v < V; ++v) {
      if ((v & j) == 0) {
        ce(rp[v], rp[v | j]);
        ce(rt[v], rt[v | j]);
      }
    }
  }
}

// (256,3): ~170 VGPR headroom. (256,4) made the allocator spill ~20 regs
// (WRITE_SIZE 0.25 -> 43 MB in round 7); DS pipe is per-CU so the lost
// wave/SIMD costs less than the spill did.
__global__ __launch_bounds__(THREADS, 3) void sort_mse_kernel(
    const float* __restrict__ pred, const float* __restrict__ targ,
    float* __restrict__ out) {
  const int lane = threadIdx.x & 63;
  const int wave = threadIdx.x >> 6;
  const int row = blockIdx.x * WPB + wave;
  const size_t base = (size_t)row * NCOL + (size_t)lane * V;

  float rp[V], rt[V];
  const float4* p4 = (const float4*)(pred + base);
  const float4* t4 = (const float4*)(targ + base);
#pragma unroll
  for (int q = 0; q < V / 4; ++q) {
    const float4 a = p4[q];
    rp[4 * q + 0] = a.x; rp[4 * q + 1] = a.y;
    rp[4 * q + 2] = a.z; rp[4 * q + 3] = a.w;
    const float4 b = t4[q];
    rt[4 * q + 0] = b.x; rt[4 * q + 1] = b.y;
    rt[4 * q + 2] = b.z; rt[4 * q + 3] = b.w;
  }

  // ---- Phase 1: stages k = 2..32, fully in-lane, fully static ----
#pragma unroll
  for (int k = 2; k <= V; k <<= 1) {
#pragma unroll
    for (int v = 0; v < V; ++v) {
      if ((v & (k >> 1)) == 0) {
        ce(rp[v], rp[v ^ (k - 1)]);
        ce(rt[v], rt[v ^ (k - 1)]);
      }
    }
#pragma unroll
    for (int j = k >> 2; j >= 1; j >>= 1) {
#pragma unroll
      for (int v = 0; v < V; ++v) {
        if ((v & j) == 0) {
          ce(rp[v], rp[v | j]);
          ce(rt[v], rt[v | j]);
        }
      }
    }
  }

  // ---- Phase 2: merge stages kb = k/64 = 1..32 ----
  // Compact runtime loops (full unroll regressed 152->171 us: I-cache).
  // lane-masks {1,2,3,7,15} -> DPP (per-SIMD VALU pipe),
  // {4,8,16,31,63} -> ds_bpermute (shared per-CU DS pipe).
#pragma unroll 1
  for (int kb = 1; kb <= 32; kb <<= 1) {
    const float cf = dirc(lane, kb);
    if (kb == 1) {
      dpp_flip_pass<DPP_XOR1>(rp, cf);  dpp_flip_pass<DPP_XOR1>(rt, cf);
    } else if (kb == 2) {
      dpp_flip_pass<DPP_XOR3>(rp, cf);  dpp_flip_pass<DPP_XOR3>(rt, cf);
    } else if (kb == 4) {
      dpp_flip_pass<DPP_XOR7>(rp, cf);  dpp_flip_pass<DPP_XOR7>(rt, cf);
    } else if (kb == 8) {
      dpp_flip_pass<DPP_XOR15>(rp, cf); dpp_flip_pass<DPP_XOR15>(rt, cf);
    } else {
      const int a = ((lane ^ (2 * kb - 1)) << 2);
      ds_flip_pass(rp, a, cf); ds_flip_pass(rt, a, cf);
    }
#pragma unroll 1
    for (int m = kb >> 1; m >= 1; m >>= 1) {
      const float c = dirc(lane, m);
      if (m == 1) {
        dpp_xor_pass<DPP_XOR1>(rp, c); dpp_xor_pass<DPP_XOR1>(rt, c);
      } else if (m == 2) {
        dpp_xor_pass<DPP_XOR2>(rp, c); dpp_xor_pass<DPP_XOR2>(rt, c);
      } else {
        const int a = ((lane ^ m) << 2);
        ds_xor_pass(rp, a, c); ds_xor_pass(rt, a, c);
      }
    }
    inlane_tail(rp, rt);
  }

  // ranks are matched at identical (lane, v) after both sorts
  float acc = 0.f;
#pragma unroll
  for (int v = 0; v < V; ++v) {
    const float d = rp[v] - rt[v];
    acc = fmaf(d, d, acc);
  }
#pragma unroll
  for (int off = 32; off > 0; off >>= 1) acc += __shfl_down(acc, off, 64);
  if (lane == 0) {
    unsafeAtomicAdd(out, acc * (1.0f / ((float)ROWS * (float)NCOL)));
  }
}

extern "C" void kernel_launch(void* const* d_in, const int* in_sizes, int n_in,
                              void* d_out, int out_size, void* d_ws, size_t ws_size,
                              hipStream_t stream) {
  const float* pred = (const float*)d_in[0];
  const float* targ = (const float*)d_in[1];
  float* out = (float*)d_out;

  hipMemsetAsync(out, 0, sizeof(float), stream);  // d_out is re-poisoned 0xAA
  sort_mse_kernel<<<ROWS / WPB, THREADS, 0, stream>>>(pred, targ, out);
}